// Round 1
// baseline (92.606 us; speedup 1.0000x reference)
//
#include <hip/hip_runtime.h>
#include <math.h>

// NoisyTopkRouter: B=4 S=4096 D=2048 E=16 K=2, TEMPERATURE=1
// rows = B*S = 16384
// out layout (all fp32): router_output [16384*16] | indices-as-float [16384*2] | aux_loss [1]

#define NROWS 16384
#define DDIM 2048
#define NEXP 16
#define TILE_ROWS 64
#define WAVE_D 512
#define CHUNK 32
#define NCHUNK 16          // 512 / 32
#define XSTRIDE 36         // padded LDS row stride (floats): conflict-free reads
#define IDX_OFF 262144     // 16384*16
#define AUX_OFF 294912     // IDX_OFF + 16384*2

__global__ __launch_bounds__(256) void router_main(
    const float* __restrict__ x, const float* __restrict__ wr,
    const float* __restrict__ br, const float* __restrict__ bn_,
    const float* __restrict__ wn, const float* __restrict__ eps,
    float* __restrict__ out, float* __restrict__ wsp);

// NOTE: parameter order fixed below in the real definition (wr, br, wn, bn, eps).

__global__ __launch_bounds__(256) void router_main_k(
    const float* __restrict__ x, const float* __restrict__ wr,
    const float* __restrict__ br, const float* __restrict__ wn,
    const float* __restrict__ bn, const float* __restrict__ eps,
    float* __restrict__ out, float* __restrict__ wsp) {
  // per-wave staging regions: x tile [64][36] (2304 floats) + w tile [32][36] (1152 floats)
  __shared__ float smem[4 * 3456];  // 55296 B

  const int tid  = threadIdx.x;
  const int wave = tid >> 6;
  const int lane = tid & 63;
  const int rg   = lane >> 3;   // 0..7  -> owns rows {rg + 8*i}
  const int q    = lane & 7;    // 0..7  -> owns cols {4q .. 4q+3} of 32 (route|noise)
  const int row_base = blockIdx.x * TILE_ROWS;

  float* xs  = smem + wave * 3456;          // [64][XSTRIDE]
  float* wsh = xs + TILE_ROWS * XSTRIDE;    // [32][XSTRIDE]: cols 0..15 route, 16..31 noise

  const float* xptr = x  + (size_t)row_base * DDIM + wave * WAVE_D;
  const float* wrp  = wr + (size_t)(wave * WAVE_D) * NEXP;
  const float* wnp  = wn + (size_t)(wave * WAVE_D) * NEXP;

  float4 acc[8];
  #pragma unroll
  for (int i = 0; i < 8; ++i) acc[i] = make_float4(0.f, 0.f, 0.f, 0.f);

  #pragma unroll 2
  for (int k = 0; k < NCHUNK; ++k) {
    const int dbase = k * CHUNK;
    // ---- stage x chunk: 64 rows x 32 d = 512 float4, 8 per lane ----
    #pragma unroll
    for (int t = 0; t < 8; ++t) {
      int f  = lane + 64 * t;
      int r  = f >> 3;          // 8 float4 per row
      int dc = (f & 7) * 4;
      float4 v = *(const float4*)(xptr + (size_t)r * DDIM + dbase + dc);
      *(float4*)(xs + r * XSTRIDE + dc) = v;
    }
    // ---- stage w chunk: 32 d x 16 e each matrix = 128 float4 each ----
    #pragma unroll
    for (int t = 0; t < 2; ++t) {
      int f  = lane + 64 * t;
      int dl = f >> 2;
      int e4 = (f & 3) * 4;
      float4 vr = *(const float4*)(wrp + (size_t)(dbase + dl) * NEXP + e4);
      *(float4*)(wsh + dl * XSTRIDE + e4) = vr;
      float4 vn = *(const float4*)(wnp + (size_t)(dbase + dl) * NEXP + e4);
      *(float4*)(wsh + dl * XSTRIDE + 16 + e4) = vn;
    }
    // same-wave LDS dependency: compiler inserts lgkmcnt waits (no barrier needed,
    // each wave has a private staging region).
    // ---- compute: 32 d, 8 rows x 4 cols per thread ----
    #pragma unroll
    for (int dd = 0; dd < CHUNK; dd += 4) {
      float4 w0 = *(const float4*)(wsh + (dd + 0) * XSTRIDE + q * 4);
      float4 w1 = *(const float4*)(wsh + (dd + 1) * XSTRIDE + q * 4);
      float4 w2 = *(const float4*)(wsh + (dd + 2) * XSTRIDE + q * 4);
      float4 w3 = *(const float4*)(wsh + (dd + 3) * XSTRIDE + q * 4);
      #pragma unroll
      for (int i = 0; i < 8; ++i) {
        float4 xv = *(const float4*)(xs + (rg + 8 * i) * XSTRIDE + dd);
        acc[i].x = fmaf(xv.w, w3.x, fmaf(xv.z, w2.x, fmaf(xv.y, w1.x, fmaf(xv.x, w0.x, acc[i].x))));
        acc[i].y = fmaf(xv.w, w3.y, fmaf(xv.z, w2.y, fmaf(xv.y, w1.y, fmaf(xv.x, w0.y, acc[i].y))));
        acc[i].z = fmaf(xv.w, w3.z, fmaf(xv.z, w2.z, fmaf(xv.y, w1.z, fmaf(xv.x, w0.z, acc[i].z))));
        acc[i].w = fmaf(xv.w, w3.w, fmaf(xv.z, w2.w, fmaf(xv.y, w1.w, fmaf(xv.x, w0.w, acc[i].w))));
      }
    }
  }

  // ---- cross-wave reduction + per-row epilogue ----
  __syncthreads();  // all waves done with their staging regions
  float* ob = smem + wave * 2304;  // [64][XSTRIDE] per wave partials
  #pragma unroll
  for (int i = 0; i < 8; ++i)
    *(float4*)(ob + (rg + 8 * i) * XSTRIDE + q * 4) = acc[i];
  __syncthreads();

  if (tid < 64) {
    const int row_l = tid;
    const int row_g = row_base + row_l;
    float c[32];
    #pragma unroll
    for (int g = 0; g < 8; ++g) {
      float4 a0 = *(const float4*)(smem + 0 * 2304 + row_l * XSTRIDE + g * 4);
      float4 a1 = *(const float4*)(smem + 1 * 2304 + row_l * XSTRIDE + g * 4);
      float4 a2 = *(const float4*)(smem + 2 * 2304 + row_l * XSTRIDE + g * 4);
      float4 a3 = *(const float4*)(smem + 3 * 2304 + row_l * XSTRIDE + g * 4);
      c[g * 4 + 0] = (a0.x + a1.x) + (a2.x + a3.x);
      c[g * 4 + 1] = (a0.y + a1.y) + (a2.y + a3.y);
      c[g * 4 + 2] = (a0.z + a1.z) + (a2.z + a3.z);
      c[g * 4 + 3] = (a0.w + a1.w) + (a2.w + a3.w);
    }

    float brv[16], bnv[16], ev[16];
    #pragma unroll
    for (int g = 0; g < 4; ++g) {
      *(float4*)(brv + g * 4) = *(const float4*)(br + g * 4);
      *(float4*)(bnv + g * 4) = *(const float4*)(bn + g * 4);
      *(float4*)(ev  + g * 4) = *(const float4*)(eps + (size_t)row_g * NEXP + g * 4);
    }

    float s[16];
    #pragma unroll
    for (int e = 0; e < 16; ++e) {
      float lg = c[e] + brv[e];
      float nz = c[16 + e] + bnv[e];
      // stable softplus = max(z,0) + log1p(exp(-|z|))
      float sp = fmaxf(nz, 0.f) + log1pf(expf(-fabsf(nz)));
      s[e] = lg + ev[e] * sp;   // TEMPERATURE == 1
    }

    // top-2 (ties -> lowest index, matching lax.top_k)
    float b1 = s[0]; int i1 = 0;
    #pragma unroll
    for (int e = 1; e < 16; ++e) { if (s[e] > b1) { b1 = s[e]; i1 = e; } }
    float b2 = -INFINITY; int i2 = 0;
    #pragma unroll
    for (int e = 0; e < 16; ++e) { if (e != i1 && s[e] > b2) { b2 = s[e]; i2 = e; } }

    float t2 = expf(b2 - b1);
    float p1 = 1.f / (1.f + t2);
    float p2 = t2 / (1.f + t2);

    float v[16];
    #pragma unroll
    for (int e = 0; e < 16; ++e)
      v[e] = (e == i1) ? p1 : ((e == i2) ? p2 : 0.f);

    float* orow = out + (size_t)row_g * NEXP;
    *(float4*)(orow + 0)  = make_float4(v[0], v[1], v[2], v[3]);
    *(float4*)(orow + 4)  = make_float4(v[4], v[5], v[6], v[7]);
    *(float4*)(orow + 8)  = make_float4(v[8], v[9], v[10], v[11]);
    *(float4*)(orow + 12) = make_float4(v[12], v[13], v[14], v[15]);

    float* oidx = out + IDX_OFF + (size_t)row_g * 2;
    *(float2*)oidx = make_float2((float)i1, (float)i2);

    // per-block expert-prob sums (64 rows) via butterfly
    #pragma unroll
    for (int m = 1; m < 64; m <<= 1) {
      #pragma unroll
      for (int e = 0; e < 16; ++e) v[e] += __shfl_xor(v[e], m, 64);
    }
    if (tid == 0) {
      float* wp = wsp + (size_t)blockIdx.x * 16;
      *(float4*)(wp + 0)  = make_float4(v[0], v[1], v[2], v[3]);
      *(float4*)(wp + 4)  = make_float4(v[4], v[5], v[6], v[7]);
      *(float4*)(wp + 8)  = make_float4(v[8], v[9], v[10], v[11]);
      *(float4*)(wp + 12) = make_float4(v[12], v[13], v[14], v[15]);
    }
  }
}

__global__ void router_aux_k(const float* __restrict__ wsp, float* __restrict__ out_aux) {
  __shared__ float red[16][17];
  __shared__ float sq[16];
  const int t = threadIdx.x;
  const int e = t & 15;
  const int g = t >> 4;
  float ssum = 0.f;
  #pragma unroll
  for (int b = 0; b < 16; ++b) ssum += wsp[(size_t)(g * 16 + b) * 16 + e];
  red[g][e] = ssum;
  __syncthreads();
  if (t < 16) {
    float tot = 0.f;
    #pragma unroll
    for (int gg = 0; gg < 16; ++gg) tot += red[gg][t];
    float diff = tot * (1.f / 16384.f) - 0.0625f;
    sq[t] = diff * diff;
  }
  __syncthreads();
  if (t == 0) {
    float a = 0.f;
    #pragma unroll
    for (int i = 0; i < 16; ++i) a += sq[i];
    *out_aux = a;
  }
}

extern "C" void kernel_launch(void* const* d_in, const int* in_sizes, int n_in,
                              void* d_out, int out_size, void* d_ws, size_t ws_size,
                              hipStream_t stream) {
  const float* x   = (const float*)d_in[0];
  const float* wr  = (const float*)d_in[1];
  const float* br  = (const float*)d_in[2];
  const float* wn  = (const float*)d_in[3];
  const float* bn  = (const float*)d_in[4];
  const float* eps = (const float*)d_in[5];
  float* out = (float*)d_out;
  float* wsp = (float*)d_ws;  // 256 blocks * 16 floats = 16 KB partials

  router_main_k<<<256, 256, 0, stream>>>(x, wr, br, wn, bn, eps, out, wsp);
  router_aux_k<<<1, 256, 0, stream>>>(wsp, out + AUX_OFF);
}